// Round 13
// baseline (108.306 us; speedup 1.0000x reference)
//
#include <hip/hip_runtime.h>

// Problem sizes
#define NROWS 8192   // B*T
#define MCB   1024   // codebook size M
#define DD    256    // feature dim D
#define TT    128    // T
#define BB    64     // B

// ws offsets (in floats)
#define OFF_DA      0ul
#define OFF_DV      8388608ul
#define OFF_XX_A    16777216ul
#define OFF_XX_V    16785408ul
#define OFF_EE      16793600ul
#define OFF_SMIN_A  16794624ul
#define OFF_LZ1_A   16802816ul
#define OFF_IZ2_A   16811008ul
#define OFF_IDX_A   16819200ul
#define OFF_SMIN_V  16827392ul
#define OFF_LZ1_V   16835584ul
#define OFF_IZ2_V   16843776ul
#define OFF_IDX_V   16851968ul
#define OFF_S1      16860160ul
#define OFF_S2      17384448ul
#define OFF_PART    17908736ul
#define OFF_MAX     17908992ul
#define OFF_PACC    17909000ul   // 256 doubles, per-block loss partials
// split-bf16 planes (ushort arrays), 16B-aligned float offsets:
#define OFF_HIA     17909504ul   // 8192*256 ushorts = 1048576 floats
#define OFF_LOA     (OFF_HIA + 1048576ul)
#define OFF_HIV     (OFF_HIA + 2097152ul)
#define OFF_LOV     (OFF_HIA + 3145728ul)
#define OFF_HIE     (OFF_HIA + 4194304ul)   // 1024*256 ushorts = 131072 floats
#define OFF_LOE     (OFF_HIE + 131072ul)
// NOTE: after k_rowstats, the D rows are overwritten in place with bf16
// planes: row n = [ pa[1024] | wv[1024] ] ushorts (pa=exp(-2w), wv=w).

typedef __attribute__((ext_vector_type(8))) short bf16x8;
typedef __attribute__((ext_vector_type(4))) float f32x4;

// ---------------------------------------------------------------------------
__device__ __forceinline__ void gload_lds16u(const ushort* gsrc, ushort* ldst) {
  __builtin_amdgcn_global_load_lds(
      (const __attribute__((address_space(1))) void*)gsrc,
      (__attribute__((address_space(3))) void*)ldst, 16, 0, 0);
}
__device__ __forceinline__ ushort bf16_rne(float x) {
  unsigned u = __float_as_uint(x);
  unsigned r = u + 0x7FFFu + ((u >> 16) & 1u);
  return (ushort)(r >> 16);
}
__device__ __forceinline__ float bf16_f(ushort h) {
  return __uint_as_float((unsigned)h << 16);
}

// ---------------------------------------------------------------------------
// Kernel 1: row sums of squares (fp64 accumulate) + split-bf16 hi/lo planes.
__global__ void k_sumsq(const float* __restrict__ A, const float* __restrict__ V,
                        const float* __restrict__ E, float* __restrict__ ws) {
  const int lane = threadIdx.x & 63;
  const int wid  = threadIdx.x >> 6;
  const int row = blockIdx.x * 4 + wid;   // 0..17407
  const float* src; float* dst; ushort* hi; ushort* lo; int r;
  if (row < 8192)       { src = A; r = row;         dst = ws + OFF_XX_A;
                          hi = (ushort*)(ws + OFF_HIA); lo = (ushort*)(ws + OFF_LOA); }
  else if (row < 16384) { src = V; r = row - 8192;  dst = ws + OFF_XX_V;
                          hi = (ushort*)(ws + OFF_HIV); lo = (ushort*)(ws + OFF_LOV); }
  else                  { src = E; r = row - 16384; dst = ws + OFF_EE;
                          hi = (ushort*)(ws + OFF_HIE); lo = (ushort*)(ws + OFF_LOE); }
  float4 x = *(const float4*)(src + (size_t)r * DD + lane * 4);
  ushort4 h, l;
  h.x = bf16_rne(x.x); l.x = bf16_rne(x.x - bf16_f(h.x));
  h.y = bf16_rne(x.y); l.y = bf16_rne(x.y - bf16_f(h.y));
  h.z = bf16_rne(x.z); l.z = bf16_rne(x.z - bf16_f(h.z));
  h.w = bf16_rne(x.w); l.w = bf16_rne(x.w - bf16_f(h.w));
  *(ushort4*)(hi + (size_t)r * DD + lane * 4) = h;
  *(ushort4*)(lo + (size_t)r * DD + lane * 4) = l;
  double acc = (double)x.x * x.x + (double)x.y * x.y +
               (double)x.z * x.z + (double)x.w * x.w;
  #pragma unroll
  for (int off = 32; off; off >>= 1) acc += __shfl_xor(acc, off);
  if (lane == 0) dst[r] = (float)acc;
}

// ---------------------------------------------------------------------------
// Kernel 2: dist GEMM via split-bf16 MFMA (hi*hi + hi*lo + lo*hi).
// (round-10 structure, unchanged — verified absmax 0.0)
__global__ __launch_bounds__(256) void k_dist(const float* __restrict__ A,
    const float* __restrict__ V, const float* __restrict__ E,
    float* __restrict__ ws) {
  const int z = blockIdx.z;
  const ushort* Xhi = (const ushort*)(ws + (z ? OFF_HIV : OFF_HIA));
  const ushort* Xlo = (const ushort*)(ws + (z ? OFF_LOV : OFF_LOA));
  const ushort* Ehi = (const ushort*)(ws + OFF_HIE);
  const ushort* Elo = (const ushort*)(ws + OFF_LOE);
  const float* xx = ws + (z ? OFF_XX_V : OFF_XX_A);
  const float* ee = ws + OFF_EE;
  float* Dst = ws + (z ? OFF_DV : OFF_DA);

  __shared__ __align__(16) ushort LAhi[128 * 32];
  __shared__ __align__(16) ushort LAlo[128 * 32];
  __shared__ __align__(16) ushort LBhi[128 * 32];
  __shared__ __align__(16) ushort LBlo[128 * 32];

  const int tid = threadIdx.x;
  const int bid = blockIdx.y * 8 + blockIdx.x;        // 0..511
  const int sw  = (bid & 7) * 64 + (bid >> 3);
  const int colb = sw & 7, rowb = sw >> 3;
  const int row0 = rowb * 128;
  const int col0 = colb * 128;

  const int wv = tid >> 6, lane = tid & 63;
  const int wr = wv >> 1, wc = wv & 1;                // wave tile (64x64)
  const int rl = lane & 15, kg = lane >> 4;

  const int c0 = tid, c1 = 256 + tid;
  const int r0 = c0 >> 2, lg0 = (c0 & 3) ^ ((r0 >> 1) & 3);
  const int r1 = c1 >> 2, lg1 = (c1 & 3) ^ ((r1 >> 1) & 3);
  const ushort* gAhi0 = Xhi + (size_t)(row0 + r0) * DD + lg0 * 8;
  const ushort* gAhi1 = Xhi + (size_t)(row0 + r1) * DD + lg1 * 8;
  const ushort* gAlo0 = Xlo + (size_t)(row0 + r0) * DD + lg0 * 8;
  const ushort* gAlo1 = Xlo + (size_t)(row0 + r1) * DD + lg1 * 8;
  const ushort* gBhi0 = Ehi + (size_t)(col0 + r0) * DD + lg0 * 8;
  const ushort* gBhi1 = Ehi + (size_t)(col0 + r1) * DD + lg1 * 8;
  const ushort* gBlo0 = Elo + (size_t)(col0 + r0) * DD + lg0 * 8;
  const ushort* gBlo1 = Elo + (size_t)(col0 + r1) * DD + lg1 * 8;
  const int d0 = c0 * 8, d1 = c1 * 8;

  int aidx[4], bidx[4];
  #pragma unroll
  for (int f = 0; f < 4; ++f) {
    int ra = wr * 64 + f * 16 + rl;
    aidx[f] = ra * 32 + ((kg ^ ((ra >> 1) & 3)) << 3);
    int rb = wc * 64 + f * 16 + rl;
    bidx[f] = rb * 32 + ((kg ^ ((rb >> 1) & 3)) << 3);
  }

  f32x4 acc[4][4] = {};

  for (int t = 0; t < 8; ++t) {
    const int kc = t * 32;
    gload_lds16u(gAhi0 + kc, &LAhi[d0]);
    gload_lds16u(gAhi1 + kc, &LAhi[d1]);
    gload_lds16u(gAlo0 + kc, &LAlo[d0]);
    gload_lds16u(gAlo1 + kc, &LAlo[d1]);
    gload_lds16u(gBhi0 + kc, &LBhi[d0]);
    gload_lds16u(gBhi1 + kc, &LBhi[d1]);
    gload_lds16u(gBlo0 + kc, &LBlo[d0]);
    gload_lds16u(gBlo1 + kc, &LBlo[d1]);
    __syncthreads();
    __builtin_amdgcn_s_setprio(1);
    bf16x8 ahi[4], alo[4], bhi[4], blo[4];
    #pragma unroll
    for (int f = 0; f < 4; ++f) {
      ahi[f] = *(const bf16x8*)(&LAhi[aidx[f]]);
      alo[f] = *(const bf16x8*)(&LAlo[aidx[f]]);
      bhi[f] = *(const bf16x8*)(&LBhi[bidx[f]]);
      blo[f] = *(const bf16x8*)(&LBlo[bidx[f]]);
    }
    #pragma unroll
    for (int fr = 0; fr < 4; ++fr)
      #pragma unroll
      for (int fc = 0; fc < 4; ++fc) {
        acc[fr][fc] = __builtin_amdgcn_mfma_f32_16x16x32_bf16(
            ahi[fr], bhi[fc], acc[fr][fc], 0, 0, 0);
        acc[fr][fc] = __builtin_amdgcn_mfma_f32_16x16x32_bf16(
            ahi[fr], blo[fc], acc[fr][fc], 0, 0, 0);
        acc[fr][fc] = __builtin_amdgcn_mfma_f32_16x16x32_bf16(
            alo[fr], bhi[fc], acc[fr][fc], 0, 0, 0);
      }
    __builtin_amdgcn_s_setprio(0);
    __syncthreads();
  }

  float xn[4][4];
  #pragma unroll
  for (int fr = 0; fr < 4; ++fr)
    #pragma unroll
    for (int v = 0; v < 4; ++v)
      xn[fr][v] = xx[row0 + wr * 64 + fr * 16 + kg * 4 + v];
  #pragma unroll
  for (int fc = 0; fc < 4; ++fc) {
    const int m = col0 + wc * 64 + fc * 16 + rl;
    const float em = ee[m];
    #pragma unroll
    for (int fr = 0; fr < 4; ++fr) {
      #pragma unroll
      for (int v = 0; v < 4; ++v) {
        const int n = row0 + wr * 64 + fr * 16 + kg * 4 + v;
        Dst[(size_t)n * MCB + m] = (em + xn[fr][v]) - 2.0f * acc[fr][fc][v];
      }
    }
  }
}

// ---------------------------------------------------------------------------
// Kernel 3: per-row stats (min/argmin, softmax denominators) + quantize write
// + IN-PLACE transform: overwrite the row's 4 KB with bf16 [pa[1024]|wv[1024]]
__global__ void k_rowstats(const float* __restrict__ A, const float* __restrict__ V,
                           const float* __restrict__ E, float* __restrict__ ws,
                           float* __restrict__ out) {
  const int z = blockIdx.y;
  float* Dm = ws + (z ? OFF_DV : OFF_DA);
  const float* X  = z ? V : A;
  float* smin_o = ws + (z ? OFF_SMIN_V : OFF_SMIN_A);
  float* lz1_o  = ws + (z ? OFF_LZ1_V  : OFF_LZ1_A);
  float* iz2_o  = ws + (z ? OFF_IZ2_V  : OFF_IZ2_A);
  int*   idx_o  = (int*)(ws + (z ? OFF_IDX_V : OFF_IDX_A));
  float* qout = out + 1 + (size_t)z * ((size_t)NROWS * DD);

  const int lane = threadIdx.x & 63, wid = threadIdx.x >> 6;
  const int n = blockIdx.x * 4 + wid;
  float* drow = Dm + (size_t)n * MCB;

  float v[16];
  #pragma unroll
  for (int c = 0; c < 4; ++c) {
    float4 t = *(const float4*)(drow + c * 256 + lane * 4);
    v[c*4+0] = t.x; v[c*4+1] = t.y; v[c*4+2] = t.z; v[c*4+3] = t.w;
  }
  float bv = 3.4e38f; int bi = 0;
  #pragma unroll
  for (int c = 0; c < 4; ++c)
    #pragma unroll
    for (int j = 0; j < 4; ++j) {
      float val = v[c*4+j];
      int m = c * 256 + lane * 4 + j;
      if (val < bv) { bv = val; bi = m; }
    }
  #pragma unroll
  for (int off = 32; off; off >>= 1) {
    float ov = __shfl_xor(bv, off);
    int   oi = __shfl_xor(bi, off);
    if (ov < bv || (ov == bv && oi < bi)) { bv = ov; bi = oi; }
  }
  float smin = sqrtf(fmaxf(bv, 0.0f));
  float w[16], e2[16];
  float z1 = 0.f, z2 = 0.f;
  #pragma unroll
  for (int q = 0; q < 16; ++q) {
    w[q] = sqrtf(fmaxf(v[q], 0.0f)) - smin;
    z1 += __expf(-w[q]);
    e2[q] = __expf(-2.0f * w[q]);
    z2 += e2[q];
  }
  #pragma unroll
  for (int off = 32; off; off >>= 1) {
    z1 += __shfl_xor(z1, off);
    z2 += __shfl_xor(z2, off);
  }
  if (lane == 0) {
    smin_o[n] = smin;
    lz1_o[n]  = __logf(z1);
    iz2_o[n]  = 1.0f / z2;
    idx_o[n]  = bi;
  }
  // in-place bf16 planes over the consumed row (wave owns row exclusively)
  ushort* prow = (ushort*)drow;
  #pragma unroll
  for (int c = 0; c < 4; ++c) {
    ushort4 hp, hw;
    hp.x = bf16_rne(e2[c*4+0]); hp.y = bf16_rne(e2[c*4+1]);
    hp.z = bf16_rne(e2[c*4+2]); hp.w = bf16_rne(e2[c*4+3]);
    hw.x = bf16_rne(w[c*4+0]);  hw.y = bf16_rne(w[c*4+1]);
    hw.z = bf16_rne(w[c*4+2]);  hw.w = bf16_rne(w[c*4+3]);
    *(ushort4*)(prow + c * 256 + lane * 4) = hp;
    *(ushort4*)(prow + 1024 + c * 256 + lane * 4) = hw;
  }
  const float* erow = E + (size_t)bi * DD;
  const float* xrow = X + (size_t)n * DD;
  #pragma unroll
  for (int p = 0; p < 4; ++p) {
    int dd = p * 64 + lane;
    float xv = xrow[dd];
    float ev = erow[dd];
    qout[(size_t)n * DD + dd] = xv + (ev - xv);
  }
}

// ---------------------------------------------------------------------------
// Kernel 4 (barrier-free MFMA GEMM): S[t,b,c] = -izP[b]*(sum_m pa*wv) - lzQ[c]
// Operand fragments loaded DIRECTLY global->registers (no LDS, no K-loop
// barriers): each lane's fragment is a contiguous 16 B at row (b*128+t),
// granule kg — identical bytes/order to round 12 -> S bit-identical.
// 8 waves: b-tile (wv&3)*16, c-half (wv>>2)*32; 16 m-chunks of 64.
// Redundant reads (pa x2, wv x4) hit L2/L3 (planes just written).
__global__ __launch_bounds__(512) void k_sgemm(float* __restrict__ ws) {
  const int z = blockIdx.y;
  const int t = blockIdx.x;
  const ushort* P = (const ushort*)(ws + (z ? OFF_DV : OFF_DA));  // pa rows
  const ushort* Q = (const ushort*)(ws + (z ? OFF_DA : OFF_DV));  // wv rows
  const float* iz2_p  = ws + (z ? OFF_IZ2_V  : OFF_IZ2_A);
  const float* lz1_q  = ws + (z ? OFF_LZ1_A  : OFF_LZ1_V);
  float* S = ws + (z ? OFF_S2 : OFF_S1);
  float* part = ws + OFF_PART;

  __shared__ float redmin[8];

  const int tid = threadIdx.x;
  const int wv = tid >> 6, lane = tid & 63;
  const int rl = lane & 15, kg = lane >> 4;
  const int bt  = (wv & 3) * 16;      // wave b-tile base
  const int ctl = (wv >> 2) * 32;     // wave c-half base

  const int ra  = bt + rl;            // A row (b index)
  const int rb0 = ctl + rl, rb1 = ctl + 16 + rl;
  const ushort* pa_b = P + ((size_t)ra  * TT + t) * 2048 + kg * 8;
  const ushort* wq0b = Q + ((size_t)rb0 * TT + t) * 2048 + 1024 + kg * 8;
  const ushort* wq1b = Q + ((size_t)rb1 * TT + t) * 2048 + 1024 + kg * 8;

  f32x4 acc0 = {}, acc1 = {};

  #pragma unroll 4
  for (int ch = 0; ch < 16; ++ch) {
    const int off = ch * 64;
    bf16x8 a0  = *(const bf16x8*)(pa_b + off);
    bf16x8 a1  = *(const bf16x8*)(pa_b + off + 32);
    bf16x8 b00 = *(const bf16x8*)(wq0b + off);
    bf16x8 b01 = *(const bf16x8*)(wq0b + off + 32);
    bf16x8 b10 = *(const bf16x8*)(wq1b + off);
    bf16x8 b11 = *(const bf16x8*)(wq1b + off + 32);
    acc0 = __builtin_amdgcn_mfma_f32_16x16x32_bf16(a0, b00, acc0, 0, 0, 0);
    acc1 = __builtin_amdgcn_mfma_f32_16x16x32_bf16(a0, b10, acc1, 0, 0, 0);
    acc0 = __builtin_amdgcn_mfma_f32_16x16x32_bf16(a1, b01, acc0, 0, 0, 0);
    acc1 = __builtin_amdgcn_mfma_f32_16x16x32_bf16(a1, b11, acc1, 0, 0, 0);
  }

  // epilogue: S = -izP[b]*G - lzQ[c]; fused block-min
  const float lzq0 = lz1_q[(size_t)rb0 * TT + t];
  const float lzq1 = lz1_q[(size_t)rb1 * TT + t];
  float mn = 3.4e38f;
  #pragma unroll
  for (int v = 0; v < 4; ++v) {
    const int b = bt + kg * 4 + v;
    const float izb = iz2_p[(size_t)b * TT + t];
    float s0 = -izb * acc0[v] - lzq0;
    float s1 = -izb * acc1[v] - lzq1;
    S[((size_t)t * 64 + b) * 64 + rb0] = s0;
    S[((size_t)t * 64 + b) * 64 + rb1] = s1;
    mn = fminf(mn, fminf(s0, s1));
  }
  #pragma unroll
  for (int off = 32; off; off >>= 1) mn = fminf(mn, __shfl_xor(mn, off));
  if (lane == 0) redmin[wv] = mn;
  __syncthreads();
  if (tid == 0) {
    float m = redmin[0];
    #pragma unroll
    for (int i = 1; i < 8; ++i) m = fminf(m, redmin[i]);
    part[z * 128 + t] = m;
  }
}

// ---------------------------------------------------------------------------
// Kernel 5: loss rows; Max computed in-block from part[] (fmin exact ->
// identical to the old k_sfinal reduction); per-wave register accumulation.
__global__ __launch_bounds__(256) void k_loss(float* __restrict__ ws) {
  const int lane = threadIdx.x & 63, wid = threadIdx.x >> 6;
  const float* part = ws + OFF_PART;
  __shared__ float red[4];
  __shared__ float smax[2];
  // reduce part[0..127] -> Max0 (threads 0..127), part[128..255] -> Max1
  float m = part[threadIdx.x];
  #pragma unroll
  for (int off = 32; off; off >>= 1) m = fminf(m, __shfl_xor(m, off));
  if (lane == 0) red[wid] = m;
  __syncthreads();
  if (threadIdx.x == 0)   smax[0] = -fminf(red[0], red[1]);
  if (threadIdx.x == 128) smax[1] = -fminf(red[2], red[3]);
  __syncthreads();

  const int wglobal = blockIdx.x * 4 + wid;   // 0..1023
  double acc = 0.0;
  #pragma unroll 4
  for (int r = 0; r < 16; ++r) {
    int gw = wglobal * 16 + r;                // 0..16383
    int tens = gw >> 13;
    int rem = gw & 8191;                      // t*64 + b
    const float* S = ws + (tens ? OFF_S2 : OFF_S1);
    float maxv = smax[tens];
    float ev = __expf(S[(size_t)rem * 64 + lane] + maxv);
    float sum = ev;
    #pragma unroll
    for (int off = 32; off; off >>= 1) sum += __shfl_xor(sum, off);
    float diag = __shfl(ev, rem & 63);
    if (lane == 0) acc += (double)__logf(diag / (sum + 1e-5f));
  }
  __shared__ double dred[4];
  if (lane == 0) dred[wid] = acc;
  __syncthreads();
  if (threadIdx.x == 0)
    ((double*)(ws + OFF_PACC))[blockIdx.x] = dred[0] + dred[1] + dred[2] + dred[3];
}

// Kernel 6: reduce 256 per-block partials, finalize loss
__global__ void k_fin(const float* __restrict__ ws, float* __restrict__ out) {
  const double* p = (const double*)(ws + OFF_PACC);
  const int lane = threadIdx.x & 63, wid = threadIdx.x >> 6;
  double v = p[threadIdx.x];
  #pragma unroll
  for (int off = 32; off; off >>= 1) v += __shfl_xor(v, off);
  __shared__ double red[4];
  if (lane == 0) red[wid] = v;
  __syncthreads();
  if (threadIdx.x == 0)
    out[0] = (float)(-(red[0] + red[1] + red[2] + red[3]) / 16384.0);
}

// ---------------------------------------------------------------------------
extern "C" void kernel_launch(void* const* d_in, const int* in_sizes, int n_in,
                              void* d_out, int out_size, void* d_ws, size_t ws_size,
                              hipStream_t stream) {
  const float* A = (const float*)d_in[0];
  const float* V = (const float*)d_in[1];
  const float* E = (const float*)d_in[2];
  float* out = (float*)d_out;
  float* ws  = (float*)d_ws;

  k_sumsq  <<<dim3(4352), dim3(256), 0, stream>>>(A, V, E, ws);
  k_dist   <<<dim3(8, 64, 2), dim3(256), 0, stream>>>(A, V, E, ws);
  k_rowstats<<<dim3(2048, 2), dim3(256), 0, stream>>>(A, V, E, ws, out);
  k_sgemm  <<<dim3(128, 2), dim3(512), 0, stream>>>(ws);
  k_loss   <<<dim3(256), dim3(256), 0, stream>>>(ws);
  k_fin    <<<dim3(1), dim3(256), 0, stream>>>(ws, out);
}

// Round 14
// 97.333 us; speedup vs baseline: 1.1127x; 1.1127x over previous
//
#include <hip/hip_runtime.h>

// Problem sizes
#define NROWS 8192   // B*T
#define MCB   1024   // codebook size M
#define DD    256    // feature dim D
#define TT    128    // T
#define BB    64     // B

// ws offsets (in floats)
#define OFF_DA      0ul
#define OFF_DV      8388608ul
#define OFF_XX_A    16777216ul
#define OFF_XX_V    16785408ul
#define OFF_EE      16793600ul
#define OFF_SMIN_A  16794624ul
#define OFF_LZ1_A   16802816ul
#define OFF_IZ2_A   16811008ul
#define OFF_IDX_A   16819200ul
#define OFF_SMIN_V  16827392ul
#define OFF_LZ1_V   16835584ul
#define OFF_IZ2_V   16843776ul
#define OFF_IDX_V   16851968ul
#define OFF_S1      16860160ul
#define OFF_S2      17384448ul
#define OFF_PART    17908736ul
#define OFF_MAX     17908992ul
#define OFF_PACC    17909000ul   // 256 doubles, per-block loss partials
// split-bf16 planes (ushort arrays), 16B-aligned float offsets:
#define OFF_HIA     17909504ul   // 8192*256 ushorts = 1048576 floats
#define OFF_LOA     (OFF_HIA + 1048576ul)
#define OFF_HIV     (OFF_HIA + 2097152ul)
#define OFF_LOV     (OFF_HIA + 3145728ul)
#define OFF_HIE     (OFF_HIA + 4194304ul)   // 1024*256 ushorts = 131072 floats
#define OFF_LOE     (OFF_HIE + 131072ul)
// NOTE: after k_rowstats, the D rows are overwritten in place with bf16
// planes: row n = [ pa[1024] | wv[1024] ] ushorts (pa=exp(-2w), wv=w).

typedef __attribute__((ext_vector_type(8))) short bf16x8;
typedef __attribute__((ext_vector_type(4))) float f32x4;

// ---------------------------------------------------------------------------
__device__ __forceinline__ void gload_lds16u(const ushort* gsrc, ushort* ldst) {
  __builtin_amdgcn_global_load_lds(
      (const __attribute__((address_space(1))) void*)gsrc,
      (__attribute__((address_space(3))) void*)ldst, 16, 0, 0);
}
__device__ __forceinline__ ushort bf16_rne(float x) {
  unsigned u = __float_as_uint(x);
  unsigned r = u + 0x7FFFu + ((u >> 16) & 1u);
  return (ushort)(r >> 16);
}
__device__ __forceinline__ float bf16_f(ushort h) {
  return __uint_as_float((unsigned)h << 16);
}

// ---------------------------------------------------------------------------
// Kernel 1: row sums of squares (fp64 accumulate) + split-bf16 hi/lo planes.
__global__ void k_sumsq(const float* __restrict__ A, const float* __restrict__ V,
                        const float* __restrict__ E, float* __restrict__ ws) {
  const int lane = threadIdx.x & 63;
  const int wid  = threadIdx.x >> 6;
  const int row = blockIdx.x * 4 + wid;   // 0..17407
  const float* src; float* dst; ushort* hi; ushort* lo; int r;
  if (row < 8192)       { src = A; r = row;         dst = ws + OFF_XX_A;
                          hi = (ushort*)(ws + OFF_HIA); lo = (ushort*)(ws + OFF_LOA); }
  else if (row < 16384) { src = V; r = row - 8192;  dst = ws + OFF_XX_V;
                          hi = (ushort*)(ws + OFF_HIV); lo = (ushort*)(ws + OFF_LOV); }
  else                  { src = E; r = row - 16384; dst = ws + OFF_EE;
                          hi = (ushort*)(ws + OFF_HIE); lo = (ushort*)(ws + OFF_LOE); }
  float4 x = *(const float4*)(src + (size_t)r * DD + lane * 4);
  ushort4 h, l;
  h.x = bf16_rne(x.x); l.x = bf16_rne(x.x - bf16_f(h.x));
  h.y = bf16_rne(x.y); l.y = bf16_rne(x.y - bf16_f(h.y));
  h.z = bf16_rne(x.z); l.z = bf16_rne(x.z - bf16_f(h.z));
  h.w = bf16_rne(x.w); l.w = bf16_rne(x.w - bf16_f(h.w));
  *(ushort4*)(hi + (size_t)r * DD + lane * 4) = h;
  *(ushort4*)(lo + (size_t)r * DD + lane * 4) = l;
  double acc = (double)x.x * x.x + (double)x.y * x.y +
               (double)x.z * x.z + (double)x.w * x.w;
  #pragma unroll
  for (int off = 32; off; off >>= 1) acc += __shfl_xor(acc, off);
  if (lane == 0) dst[r] = (float)acc;
}

// ---------------------------------------------------------------------------
// Kernel 2: dist GEMM via split-bf16 MFMA (hi*hi + hi*lo + lo*hi).
// R10 structure upgraded to TRUE double-buffer: stage chunk t+1 into buf^1
// before computing chunk t; ONE barrier per chunk (drains staging vmcnt and
// gates reuse). LDS 64 KB -> 2 blocks/CU. Same bytes/order -> bit-identical.
__global__ __launch_bounds__(256) void k_dist(const float* __restrict__ A,
    const float* __restrict__ V, const float* __restrict__ E,
    float* __restrict__ ws) {
  const int z = blockIdx.z;
  const ushort* Xhi = (const ushort*)(ws + (z ? OFF_HIV : OFF_HIA));
  const ushort* Xlo = (const ushort*)(ws + (z ? OFF_LOV : OFF_LOA));
  const ushort* Ehi = (const ushort*)(ws + OFF_HIE);
  const ushort* Elo = (const ushort*)(ws + OFF_LOE);
  const float* xx = ws + (z ? OFF_XX_V : OFF_XX_A);
  const float* ee = ws + OFF_EE;
  float* Dst = ws + (z ? OFF_DV : OFF_DA);

  __shared__ __align__(16) ushort LAhi[2][128 * 32];
  __shared__ __align__(16) ushort LAlo[2][128 * 32];
  __shared__ __align__(16) ushort LBhi[2][128 * 32];
  __shared__ __align__(16) ushort LBlo[2][128 * 32];

  const int tid = threadIdx.x;
  const int bid = blockIdx.y * 8 + blockIdx.x;        // 0..511
  const int sw  = (bid & 7) * 64 + (bid >> 3);
  const int colb = sw & 7, rowb = sw >> 3;
  const int row0 = rowb * 128;
  const int col0 = colb * 128;

  const int wv = tid >> 6, lane = tid & 63;
  const int wr = wv >> 1, wc = wv & 1;                // wave tile (64x64)
  const int rl = lane & 15, kg = lane >> 4;

  const int c0 = tid, c1 = 256 + tid;
  const int r0 = c0 >> 2, lg0 = (c0 & 3) ^ ((r0 >> 1) & 3);
  const int r1 = c1 >> 2, lg1 = (c1 & 3) ^ ((r1 >> 1) & 3);
  const ushort* gAhi0 = Xhi + (size_t)(row0 + r0) * DD + lg0 * 8;
  const ushort* gAhi1 = Xhi + (size_t)(row0 + r1) * DD + lg1 * 8;
  const ushort* gAlo0 = Xlo + (size_t)(row0 + r0) * DD + lg0 * 8;
  const ushort* gAlo1 = Xlo + (size_t)(row0 + r1) * DD + lg1 * 8;
  const ushort* gBhi0 = Ehi + (size_t)(col0 + r0) * DD + lg0 * 8;
  const ushort* gBhi1 = Ehi + (size_t)(col0 + r1) * DD + lg1 * 8;
  const ushort* gBlo0 = Elo + (size_t)(col0 + r0) * DD + lg0 * 8;
  const ushort* gBlo1 = Elo + (size_t)(col0 + r1) * DD + lg1 * 8;
  const int d0 = c0 * 8, d1 = c1 * 8;

  int aidx[4], bidx[4];
  #pragma unroll
  for (int f = 0; f < 4; ++f) {
    int ra = wr * 64 + f * 16 + rl;
    aidx[f] = ra * 32 + ((kg ^ ((ra >> 1) & 3)) << 3);
    int rb = wc * 64 + f * 16 + rl;
    bidx[f] = rb * 32 + ((kg ^ ((rb >> 1) & 3)) << 3);
  }

  f32x4 acc[4][4] = {};

  // prologue: stage chunk 0 -> buf 0
  gload_lds16u(gAhi0, &LAhi[0][d0]);
  gload_lds16u(gAhi1, &LAhi[0][d1]);
  gload_lds16u(gAlo0, &LAlo[0][d0]);
  gload_lds16u(gAlo1, &LAlo[0][d1]);
  gload_lds16u(gBhi0, &LBhi[0][d0]);
  gload_lds16u(gBhi1, &LBhi[0][d1]);
  gload_lds16u(gBlo0, &LBlo[0][d0]);
  gload_lds16u(gBlo1, &LBlo[0][d1]);
  __syncthreads();

  for (int t = 0; t < 8; ++t) {
    const int cur = t & 1;
    if (t < 7) {                       // stage next chunk into other buffer
      const int kc = (t + 1) * 32;
      const int nb = cur ^ 1;
      gload_lds16u(gAhi0 + kc, &LAhi[nb][d0]);
      gload_lds16u(gAhi1 + kc, &LAhi[nb][d1]);
      gload_lds16u(gAlo0 + kc, &LAlo[nb][d0]);
      gload_lds16u(gAlo1 + kc, &LAlo[nb][d1]);
      gload_lds16u(gBhi0 + kc, &LBhi[nb][d0]);
      gload_lds16u(gBhi1 + kc, &LBhi[nb][d1]);
      gload_lds16u(gBlo0 + kc, &LBlo[nb][d0]);
      gload_lds16u(gBlo1 + kc, &LBlo[nb][d1]);
    }
    __builtin_amdgcn_s_setprio(1);
    bf16x8 ahi[4], alo[4], bhi[4], blo[4];
    #pragma unroll
    for (int f = 0; f < 4; ++f) {
      ahi[f] = *(const bf16x8*)(&LAhi[cur][aidx[f]]);
      alo[f] = *(const bf16x8*)(&LAlo[cur][aidx[f]]);
      bhi[f] = *(const bf16x8*)(&LBhi[cur][bidx[f]]);
      blo[f] = *(const bf16x8*)(&LBlo[cur][bidx[f]]);
    }
    #pragma unroll
    for (int fr = 0; fr < 4; ++fr)
      #pragma unroll
      for (int fc = 0; fc < 4; ++fc) {
        acc[fr][fc] = __builtin_amdgcn_mfma_f32_16x16x32_bf16(
            ahi[fr], bhi[fc], acc[fr][fc], 0, 0, 0);
        acc[fr][fc] = __builtin_amdgcn_mfma_f32_16x16x32_bf16(
            ahi[fr], blo[fc], acc[fr][fc], 0, 0, 0);
        acc[fr][fc] = __builtin_amdgcn_mfma_f32_16x16x32_bf16(
            alo[fr], bhi[fc], acc[fr][fc], 0, 0, 0);
      }
    __builtin_amdgcn_s_setprio(0);
    __syncthreads();   // next buf staged + cur fully read -> safe to reuse
  }

  float xn[4][4];
  #pragma unroll
  for (int fr = 0; fr < 4; ++fr)
    #pragma unroll
    for (int v = 0; v < 4; ++v)
      xn[fr][v] = xx[row0 + wr * 64 + fr * 16 + kg * 4 + v];
  #pragma unroll
  for (int fc = 0; fc < 4; ++fc) {
    const int m = col0 + wc * 64 + fc * 16 + rl;
    const float em = ee[m];
    #pragma unroll
    for (int fr = 0; fr < 4; ++fr) {
      #pragma unroll
      for (int v = 0; v < 4; ++v) {
        const int n = row0 + wr * 64 + fr * 16 + kg * 4 + v;
        Dst[(size_t)n * MCB + m] = (em + xn[fr][v]) - 2.0f * acc[fr][fc][v];
      }
    }
  }
}

// ---------------------------------------------------------------------------
// Kernel 3: per-row stats (min/argmin, softmax denominators) + quantize write
// + IN-PLACE transform: overwrite the row's 4 KB with bf16 [pa[1024]|wv[1024]]
__global__ void k_rowstats(const float* __restrict__ A, const float* __restrict__ V,
                           const float* __restrict__ E, float* __restrict__ ws,
                           float* __restrict__ out) {
  const int z = blockIdx.y;
  float* Dm = ws + (z ? OFF_DV : OFF_DA);
  const float* X  = z ? V : A;
  float* smin_o = ws + (z ? OFF_SMIN_V : OFF_SMIN_A);
  float* lz1_o  = ws + (z ? OFF_LZ1_V  : OFF_LZ1_A);
  float* iz2_o  = ws + (z ? OFF_IZ2_V  : OFF_IZ2_A);
  int*   idx_o  = (int*)(ws + (z ? OFF_IDX_V : OFF_IDX_A));
  float* qout = out + 1 + (size_t)z * ((size_t)NROWS * DD);

  const int lane = threadIdx.x & 63, wid = threadIdx.x >> 6;
  const int n = blockIdx.x * 4 + wid;
  float* drow = Dm + (size_t)n * MCB;

  float v[16];
  #pragma unroll
  for (int c = 0; c < 4; ++c) {
    float4 t = *(const float4*)(drow + c * 256 + lane * 4);
    v[c*4+0] = t.x; v[c*4+1] = t.y; v[c*4+2] = t.z; v[c*4+3] = t.w;
  }
  float bv = 3.4e38f; int bi = 0;
  #pragma unroll
  for (int c = 0; c < 4; ++c)
    #pragma unroll
    for (int j = 0; j < 4; ++j) {
      float val = v[c*4+j];
      int m = c * 256 + lane * 4 + j;
      if (val < bv) { bv = val; bi = m; }
    }
  #pragma unroll
  for (int off = 32; off; off >>= 1) {
    float ov = __shfl_xor(bv, off);
    int   oi = __shfl_xor(bi, off);
    if (ov < bv || (ov == bv && oi < bi)) { bv = ov; bi = oi; }
  }
  float smin = sqrtf(fmaxf(bv, 0.0f));
  float w[16], e2[16];
  float z1 = 0.f, z2 = 0.f;
  #pragma unroll
  for (int q = 0; q < 16; ++q) {
    w[q] = sqrtf(fmaxf(v[q], 0.0f)) - smin;
    z1 += __expf(-w[q]);
    e2[q] = __expf(-2.0f * w[q]);
    z2 += e2[q];
  }
  #pragma unroll
  for (int off = 32; off; off >>= 1) {
    z1 += __shfl_xor(z1, off);
    z2 += __shfl_xor(z2, off);
  }
  if (lane == 0) {
    smin_o[n] = smin;
    lz1_o[n]  = __logf(z1);
    iz2_o[n]  = 1.0f / z2;
    idx_o[n]  = bi;
  }
  // in-place bf16 planes over the consumed row (wave owns row exclusively)
  ushort* prow = (ushort*)drow;
  #pragma unroll
  for (int c = 0; c < 4; ++c) {
    ushort4 hp, hw;
    hp.x = bf16_rne(e2[c*4+0]); hp.y = bf16_rne(e2[c*4+1]);
    hp.z = bf16_rne(e2[c*4+2]); hp.w = bf16_rne(e2[c*4+3]);
    hw.x = bf16_rne(w[c*4+0]);  hw.y = bf16_rne(w[c*4+1]);
    hw.z = bf16_rne(w[c*4+2]);  hw.w = bf16_rne(w[c*4+3]);
    *(ushort4*)(prow + c * 256 + lane * 4) = hp;
    *(ushort4*)(prow + 1024 + c * 256 + lane * 4) = hw;
  }
  const float* erow = E + (size_t)bi * DD;
  const float* xrow = X + (size_t)n * DD;
  #pragma unroll
  for (int p = 0; p < 4; ++p) {
    int dd = p * 64 + lane;
    float xv = xrow[dd];
    float ev = erow[dd];
    qout[(size_t)n * DD + dd] = xv + (ev - xv);
  }
}

// ---------------------------------------------------------------------------
// Kernel 4 (pure bf16 MFMA GEMM, R12 version): S = -izP[b]*(sum pa*wv) - lzQ[c]
// 512 threads = 8 waves (b-tile wv&3, c-half wv>>2); m-chunk 64, dbuf
// gload_lds, ONE barrier per chunk. LDS [64][64] ushort, XOR swizzle key=row&7.
__global__ __launch_bounds__(512) void k_sgemm(float* __restrict__ ws) {
  const int z = blockIdx.y;
  const int t = blockIdx.x;
  const ushort* P = (const ushort*)(ws + (z ? OFF_DV : OFF_DA));  // pa rows
  const ushort* Q = (const ushort*)(ws + (z ? OFF_DA : OFF_DV));  // wv rows
  const float* iz2_p  = ws + (z ? OFF_IZ2_V  : OFF_IZ2_A);
  const float* lz1_q  = ws + (z ? OFF_LZ1_A  : OFF_LZ1_V);
  float* S = ws + (z ? OFF_S2 : OFF_S1);
  float* part = ws + OFF_PART;

  __shared__ __align__(16) ushort PAs[2][64 * 64];
  __shared__ __align__(16) ushort WQs[2][64 * 64];
  __shared__ float redmin[8];

  const int tid = threadIdx.x;
  const int wv = tid >> 6, lane = tid & 63;
  const int rl = lane & 15, kg = lane >> 4;
  const int bt  = (wv & 3) * 16;      // wave b-tile base
  const int ctl = (wv >> 2) * 32;     // wave c-half base

  const int sr = tid >> 3, sg = tid & 7;
  const int lg = sg ^ (sr & 7);
  const ushort* gP = P + (size_t)(sr * TT + t) * 2048 + lg * 8;
  const ushort* gQ = Q + (size_t)(sr * TT + t) * 2048 + 1024 + lg * 8;
  const int dso = tid * 8;

  const int ra = bt + rl;
  const int rb0 = ctl + rl, rb1 = ctl + 16 + rl;
  int aoff[2], b0off[2], b1off[2];
  #pragma unroll
  for (int ks = 0; ks < 2; ++ks) {
    int g = ks * 4 + kg;
    aoff[ks]  = ra  * 64 + ((g ^ (ra  & 7)) * 8);
    b0off[ks] = rb0 * 64 + ((g ^ (rb0 & 7)) * 8);
    b1off[ks] = rb1 * 64 + ((g ^ (rb1 & 7)) * 8);
  }

  f32x4 acc0 = {}, acc1 = {};

  gload_lds16u(gP, &PAs[0][dso]);
  gload_lds16u(gQ, &WQs[0][dso]);
  __syncthreads();

  for (int ch = 0; ch < 16; ++ch) {
    const int cur = ch & 1;
    if (ch < 15) {
      gload_lds16u(gP + (ch + 1) * 64, &PAs[cur ^ 1][dso]);
      gload_lds16u(gQ + (ch + 1) * 64, &WQs[cur ^ 1][dso]);
    }
    __builtin_amdgcn_s_setprio(1);
    #pragma unroll
    for (int ks = 0; ks < 2; ++ks) {
      bf16x8 af = *(const bf16x8*)(&PAs[cur][aoff[ks]]);
      bf16x8 b0 = *(const bf16x8*)(&WQs[cur][b0off[ks]]);
      bf16x8 b1 = *(const bf16x8*)(&WQs[cur][b1off[ks]]);
      acc0 = __builtin_amdgcn_mfma_f32_16x16x32_bf16(af, b0, acc0, 0, 0, 0);
      acc1 = __builtin_amdgcn_mfma_f32_16x16x32_bf16(af, b1, acc1, 0, 0, 0);
    }
    __builtin_amdgcn_s_setprio(0);
    __syncthreads();   // next chunk landed + this chunk fully read
  }

  const float lzq0 = lz1_q[(size_t)rb0 * TT + t];
  const float lzq1 = lz1_q[(size_t)rb1 * TT + t];
  float mn = 3.4e38f;
  #pragma unroll
  for (int v = 0; v < 4; ++v) {
    const int b = bt + kg * 4 + v;
    const float izb = iz2_p[(size_t)b * TT + t];
    float s0 = -izb * acc0[v] - lzq0;
    float s1 = -izb * acc1[v] - lzq1;
    S[((size_t)t * 64 + b) * 64 + rb0] = s0;
    S[((size_t)t * 64 + b) * 64 + rb1] = s1;
    mn = fminf(mn, fminf(s0, s1));
  }
  #pragma unroll
  for (int off = 32; off; off >>= 1) mn = fminf(mn, __shfl_xor(mn, off));
  if (lane == 0) redmin[wv] = mn;
  __syncthreads();
  if (tid == 0) {
    float m = redmin[0];
    #pragma unroll
    for (int i = 1; i < 8; ++i) m = fminf(m, redmin[i]);
    part[z * 128 + t] = m;
  }
}

// ---------------------------------------------------------------------------
// Kernel 5: loss rows; Max computed in-block from part[] (fmin exact).
__global__ __launch_bounds__(256) void k_loss(float* __restrict__ ws) {
  const int lane = threadIdx.x & 63, wid = threadIdx.x >> 6;
  const float* part = ws + OFF_PART;
  __shared__ float red[4];
  __shared__ float smax[2];
  float m = part[threadIdx.x];
  #pragma unroll
  for (int off = 32; off; off >>= 1) m = fminf(m, __shfl_xor(m, off));
  if (lane == 0) red[wid] = m;
  __syncthreads();
  if (threadIdx.x == 0)   smax[0] = -fminf(red[0], red[1]);
  if (threadIdx.x == 128) smax[1] = -fminf(red[2], red[3]);
  __syncthreads();

  const int wglobal = blockIdx.x * 4 + wid;   // 0..1023
  double acc = 0.0;
  #pragma unroll 4
  for (int r = 0; r < 16; ++r) {
    int gw = wglobal * 16 + r;                // 0..16383
    int tens = gw >> 13;
    int rem = gw & 8191;                      // t*64 + b
    const float* S = ws + (tens ? OFF_S2 : OFF_S1);
    float maxv = smax[tens];
    float ev = __expf(S[(size_t)rem * 64 + lane] + maxv);
    float sum = ev;
    #pragma unroll
    for (int off = 32; off; off >>= 1) sum += __shfl_xor(sum, off);
    float diag = __shfl(ev, rem & 63);
    if (lane == 0) acc += (double)__logf(diag / (sum + 1e-5f));
  }
  __shared__ double dred[4];
  if (lane == 0) dred[wid] = acc;
  __syncthreads();
  if (threadIdx.x == 0)
    ((double*)(ws + OFF_PACC))[blockIdx.x] = dred[0] + dred[1] + dred[2] + dred[3];
}

// Kernel 6: reduce 256 per-block partials, finalize loss
__global__ void k_fin(const float* __restrict__ ws, float* __restrict__ out) {
  const double* p = (const double*)(ws + OFF_PACC);
  const int lane = threadIdx.x & 63, wid = threadIdx.x >> 6;
  double v = p[threadIdx.x];
  #pragma unroll
  for (int off = 32; off; off >>= 1) v += __shfl_xor(v, off);
  __shared__ double red[4];
  if (lane == 0) red[wid] = v;
  __syncthreads();
  if (threadIdx.x == 0)
    out[0] = (float)(-(red[0] + red[1] + red[2] + red[3]) / 16384.0);
}

// ---------------------------------------------------------------------------
extern "C" void kernel_launch(void* const* d_in, const int* in_sizes, int n_in,
                              void* d_out, int out_size, void* d_ws, size_t ws_size,
                              hipStream_t stream) {
  const float* A = (const float*)d_in[0];
  const float* V = (const float*)d_in[1];
  const float* E = (const float*)d_in[2];
  float* out = (float*)d_out;
  float* ws  = (float*)d_ws;

  k_sumsq  <<<dim3(4352), dim3(256), 0, stream>>>(A, V, E, ws);
  k_dist   <<<dim3(8, 64, 2), dim3(256), 0, stream>>>(A, V, E, ws);
  k_rowstats<<<dim3(2048, 2), dim3(256), 0, stream>>>(A, V, E, ws, out);
  k_sgemm  <<<dim3(128, 2), dim3(512), 0, stream>>>(ws);
  k_loss   <<<dim3(256), dim3(256), 0, stream>>>(ws);
  k_fin    <<<dim3(1), dim3(256), 0, stream>>>(ws, out);
}

// Round 15
// 96.881 us; speedup vs baseline: 1.1179x; 1.0047x over previous
//
#include <hip/hip_runtime.h>

// Problem sizes
#define NROWS 8192   // B*T
#define MCB   1024   // codebook size M
#define DD    256    // feature dim D
#define TT    128    // T
#define BB    64     // B

// ws offsets (in floats)
#define OFF_DA      0ul
#define OFF_DV      8388608ul
#define OFF_XX_A    16777216ul
#define OFF_XX_V    16785408ul
#define OFF_EE      16793600ul
#define OFF_SMIN_A  16794624ul
#define OFF_LZ1_A   16802816ul
#define OFF_IZ2_A   16811008ul
#define OFF_IDX_A   16819200ul
#define OFF_SMIN_V  16827392ul
#define OFF_LZ1_V   16835584ul
#define OFF_IZ2_V   16843776ul
#define OFF_IDX_V   16851968ul
#define OFF_S1      16860160ul
#define OFF_S2      17384448ul
#define OFF_PART    17908736ul
#define OFF_MAX     17908992ul
#define OFF_PACC    17909000ul   // 256 doubles, per-block loss partials
// split-bf16 planes (ushort arrays), 16B-aligned float offsets:
#define OFF_HIA     17909504ul   // 8192*256 ushorts = 1048576 floats
#define OFF_LOA     (OFF_HIA + 1048576ul)
#define OFF_HIV     (OFF_HIA + 2097152ul)
#define OFF_LOV     (OFF_HIA + 3145728ul)
#define OFF_HIE     (OFF_HIA + 4194304ul)   // 1024*256 ushorts = 131072 floats
#define OFF_LOE     (OFF_HIE + 131072ul)
// D-ROW PERMUTATION: D (and the in-place bf16 planes that replace it) is
// stored at PHYSICAL row pr = (n&127)*64 + (n>>7)  [t-major: pr = t*64 + b,
// where n = b*128 + t]. k_dist writes permuted; k_rowstats processes physical
// rows; k_sgemm block (t,z) reads the contiguous slab [t*64, t*64+64).
// NOTE: after k_rowstats, D rows hold bf16 [ pa[1024] | wv[1024] ] ushorts.

typedef __attribute__((ext_vector_type(8))) short bf16x8;
typedef __attribute__((ext_vector_type(4))) float f32x4;

// ---------------------------------------------------------------------------
__device__ __forceinline__ void gload_lds16u(const ushort* gsrc, ushort* ldst) {
  __builtin_amdgcn_global_load_lds(
      (const __attribute__((address_space(1))) void*)gsrc,
      (__attribute__((address_space(3))) void*)ldst, 16, 0, 0);
}
__device__ __forceinline__ ushort bf16_rne(float x) {
  unsigned u = __float_as_uint(x);
  unsigned r = u + 0x7FFFu + ((u >> 16) & 1u);
  return (ushort)(r >> 16);
}
__device__ __forceinline__ float bf16_f(ushort h) {
  return __uint_as_float((unsigned)h << 16);
}

// ---------------------------------------------------------------------------
// Kernel 1: row sums of squares (fp64 accumulate) + split-bf16 hi/lo planes.
__global__ void k_sumsq(const float* __restrict__ A, const float* __restrict__ V,
                        const float* __restrict__ E, float* __restrict__ ws) {
  const int lane = threadIdx.x & 63;
  const int wid  = threadIdx.x >> 6;
  const int row = blockIdx.x * 4 + wid;   // 0..17407
  const float* src; float* dst; ushort* hi; ushort* lo; int r;
  if (row < 8192)       { src = A; r = row;         dst = ws + OFF_XX_A;
                          hi = (ushort*)(ws + OFF_HIA); lo = (ushort*)(ws + OFF_LOA); }
  else if (row < 16384) { src = V; r = row - 8192;  dst = ws + OFF_XX_V;
                          hi = (ushort*)(ws + OFF_HIV); lo = (ushort*)(ws + OFF_LOV); }
  else                  { src = E; r = row - 16384; dst = ws + OFF_EE;
                          hi = (ushort*)(ws + OFF_HIE); lo = (ushort*)(ws + OFF_LOE); }
  float4 x = *(const float4*)(src + (size_t)r * DD + lane * 4);
  ushort4 h, l;
  h.x = bf16_rne(x.x); l.x = bf16_rne(x.x - bf16_f(h.x));
  h.y = bf16_rne(x.y); l.y = bf16_rne(x.y - bf16_f(h.y));
  h.z = bf16_rne(x.z); l.z = bf16_rne(x.z - bf16_f(h.z));
  h.w = bf16_rne(x.w); l.w = bf16_rne(x.w - bf16_f(h.w));
  *(ushort4*)(hi + (size_t)r * DD + lane * 4) = h;
  *(ushort4*)(lo + (size_t)r * DD + lane * 4) = l;
  double acc = (double)x.x * x.x + (double)x.y * x.y +
               (double)x.z * x.z + (double)x.w * x.w;
  #pragma unroll
  for (int off = 32; off; off >>= 1) acc += __shfl_xor(acc, off);
  if (lane == 0) dst[r] = (float)acc;
}

// ---------------------------------------------------------------------------
// Kernel 2: dist GEMM via split-bf16 MFMA (hi*hi + hi*lo + lo*hi).
// True double-buffer (R14); OUTPUT ROWS PERMUTED to t-major:
//   physical row pr = (n&127)*64 + rowb  (n>>7 == rowb within a tile).
__global__ __launch_bounds__(256) void k_dist(const float* __restrict__ A,
    const float* __restrict__ V, const float* __restrict__ E,
    float* __restrict__ ws) {
  const int z = blockIdx.z;
  const ushort* Xhi = (const ushort*)(ws + (z ? OFF_HIV : OFF_HIA));
  const ushort* Xlo = (const ushort*)(ws + (z ? OFF_LOV : OFF_LOA));
  const ushort* Ehi = (const ushort*)(ws + OFF_HIE);
  const ushort* Elo = (const ushort*)(ws + OFF_LOE);
  const float* xx = ws + (z ? OFF_XX_V : OFF_XX_A);
  const float* ee = ws + OFF_EE;
  float* Dst = ws + (z ? OFF_DV : OFF_DA);

  __shared__ __align__(16) ushort LAhi[2][128 * 32];
  __shared__ __align__(16) ushort LAlo[2][128 * 32];
  __shared__ __align__(16) ushort LBhi[2][128 * 32];
  __shared__ __align__(16) ushort LBlo[2][128 * 32];

  const int tid = threadIdx.x;
  const int bid = blockIdx.y * 8 + blockIdx.x;        // 0..511
  const int sw  = (bid & 7) * 64 + (bid >> 3);
  const int colb = sw & 7, rowb = sw >> 3;
  const int row0 = rowb * 128;
  const int col0 = colb * 128;

  const int wv = tid >> 6, lane = tid & 63;
  const int wr = wv >> 1, wc = wv & 1;                // wave tile (64x64)
  const int rl = lane & 15, kg = lane >> 4;

  const int c0 = tid, c1 = 256 + tid;
  const int r0 = c0 >> 2, lg0 = (c0 & 3) ^ ((r0 >> 1) & 3);
  const int r1 = c1 >> 2, lg1 = (c1 & 3) ^ ((r1 >> 1) & 3);
  const ushort* gAhi0 = Xhi + (size_t)(row0 + r0) * DD + lg0 * 8;
  const ushort* gAhi1 = Xhi + (size_t)(row0 + r1) * DD + lg1 * 8;
  const ushort* gAlo0 = Xlo + (size_t)(row0 + r0) * DD + lg0 * 8;
  const ushort* gAlo1 = Xlo + (size_t)(row0 + r1) * DD + lg1 * 8;
  const ushort* gBhi0 = Ehi + (size_t)(col0 + r0) * DD + lg0 * 8;
  const ushort* gBhi1 = Ehi + (size_t)(col0 + r1) * DD + lg1 * 8;
  const ushort* gBlo0 = Elo + (size_t)(col0 + r0) * DD + lg0 * 8;
  const ushort* gBlo1 = Elo + (size_t)(col0 + r1) * DD + lg1 * 8;
  const int d0 = c0 * 8, d1 = c1 * 8;

  int aidx[4], bidx[4];
  #pragma unroll
  for (int f = 0; f < 4; ++f) {
    int ra = wr * 64 + f * 16 + rl;
    aidx[f] = ra * 32 + ((kg ^ ((ra >> 1) & 3)) << 3);
    int rb = wc * 64 + f * 16 + rl;
    bidx[f] = rb * 32 + ((kg ^ ((rb >> 1) & 3)) << 3);
  }

  f32x4 acc[4][4] = {};

  // prologue: stage chunk 0 -> buf 0
  gload_lds16u(gAhi0, &LAhi[0][d0]);
  gload_lds16u(gAhi1, &LAhi[0][d1]);
  gload_lds16u(gAlo0, &LAlo[0][d0]);
  gload_lds16u(gAlo1, &LAlo[0][d1]);
  gload_lds16u(gBhi0, &LBhi[0][d0]);
  gload_lds16u(gBhi1, &LBhi[0][d1]);
  gload_lds16u(gBlo0, &LBlo[0][d0]);
  gload_lds16u(gBlo1, &LBlo[0][d1]);
  __syncthreads();

  for (int t = 0; t < 8; ++t) {
    const int cur = t & 1;
    if (t < 7) {                       // stage next chunk into other buffer
      const int kc = (t + 1) * 32;
      const int nb = cur ^ 1;
      gload_lds16u(gAhi0 + kc, &LAhi[nb][d0]);
      gload_lds16u(gAhi1 + kc, &LAhi[nb][d1]);
      gload_lds16u(gAlo0 + kc, &LAlo[nb][d0]);
      gload_lds16u(gAlo1 + kc, &LAlo[nb][d1]);
      gload_lds16u(gBhi0 + kc, &LBhi[nb][d0]);
      gload_lds16u(gBhi1 + kc, &LBhi[nb][d1]);
      gload_lds16u(gBlo0 + kc, &LBlo[nb][d0]);
      gload_lds16u(gBlo1 + kc, &LBlo[nb][d1]);
    }
    __builtin_amdgcn_s_setprio(1);
    bf16x8 ahi[4], alo[4], bhi[4], blo[4];
    #pragma unroll
    for (int f = 0; f < 4; ++f) {
      ahi[f] = *(const bf16x8*)(&LAhi[cur][aidx[f]]);
      alo[f] = *(const bf16x8*)(&LAlo[cur][aidx[f]]);
      bhi[f] = *(const bf16x8*)(&LBhi[cur][bidx[f]]);
      blo[f] = *(const bf16x8*)(&LBlo[cur][bidx[f]]);
    }
    #pragma unroll
    for (int fr = 0; fr < 4; ++fr)
      #pragma unroll
      for (int fc = 0; fc < 4; ++fc) {
        acc[fr][fc] = __builtin_amdgcn_mfma_f32_16x16x32_bf16(
            ahi[fr], bhi[fc], acc[fr][fc], 0, 0, 0);
        acc[fr][fc] = __builtin_amdgcn_mfma_f32_16x16x32_bf16(
            ahi[fr], blo[fc], acc[fr][fc], 0, 0, 0);
        acc[fr][fc] = __builtin_amdgcn_mfma_f32_16x16x32_bf16(
            alo[fr], bhi[fc], acc[fr][fc], 0, 0, 0);
      }
    __builtin_amdgcn_s_setprio(0);
    __syncthreads();   // next buf staged + cur fully read -> safe to reuse
  }

  float xn[4][4];
  #pragma unroll
  for (int fr = 0; fr < 4; ++fr)
    #pragma unroll
    for (int v = 0; v < 4; ++v)
      xn[fr][v] = xx[row0 + wr * 64 + fr * 16 + kg * 4 + v];
  #pragma unroll
  for (int fc = 0; fc < 4; ++fc) {
    const int m = col0 + wc * 64 + fc * 16 + rl;
    const float em = ee[m];
    #pragma unroll
    for (int fr = 0; fr < 4; ++fr) {
      #pragma unroll
      for (int v = 0; v < 4; ++v) {
        const int lr = wr * 64 + fr * 16 + kg * 4 + v;   // n & 127
        const int pr = lr * 64 + rowb;                   // permuted row
        Dst[(size_t)pr * MCB + m] = (em + xn[fr][v]) - 2.0f * acc[fr][fc][v];
      }
    }
  }
}

// ---------------------------------------------------------------------------
// Kernel 3: per-row stats + quantize write + IN-PLACE bf16 [pa|wv] planes.
// Processes PHYSICAL row r (D is t-major-permuted); logical n = (r&63)*128
// + (r>>6) indexes X/E/qout/stats.
__global__ void k_rowstats(const float* __restrict__ A, const float* __restrict__ V,
                           const float* __restrict__ E, float* __restrict__ ws,
                           float* __restrict__ out) {
  const int z = blockIdx.y;
  float* Dm = ws + (z ? OFF_DV : OFF_DA);
  const float* X  = z ? V : A;
  float* smin_o = ws + (z ? OFF_SMIN_V : OFF_SMIN_A);
  float* lz1_o  = ws + (z ? OFF_LZ1_V  : OFF_LZ1_A);
  float* iz2_o  = ws + (z ? OFF_IZ2_V  : OFF_IZ2_A);
  int*   idx_o  = (int*)(ws + (z ? OFF_IDX_V : OFF_IDX_A));
  float* qout = out + 1 + (size_t)z * ((size_t)NROWS * DD);

  const int lane = threadIdx.x & 63, wid = threadIdx.x >> 6;
  const int r = blockIdx.x * 4 + wid;            // physical row
  const int n = ((r & 63) << 7) + (r >> 6);      // logical row b*128+t
  float* drow = Dm + (size_t)r * MCB;

  float v[16];
  #pragma unroll
  for (int c = 0; c < 4; ++c) {
    float4 t = *(const float4*)(drow + c * 256 + lane * 4);
    v[c*4+0] = t.x; v[c*4+1] = t.y; v[c*4+2] = t.z; v[c*4+3] = t.w;
  }
  float bv = 3.4e38f; int bi = 0;
  #pragma unroll
  for (int c = 0; c < 4; ++c)
    #pragma unroll
    for (int j = 0; j < 4; ++j) {
      float val = v[c*4+j];
      int m = c * 256 + lane * 4 + j;
      if (val < bv) { bv = val; bi = m; }
    }
  #pragma unroll
  for (int off = 32; off; off >>= 1) {
    float ov = __shfl_xor(bv, off);
    int   oi = __shfl_xor(bi, off);
    if (ov < bv || (ov == bv && oi < bi)) { bv = ov; bi = oi; }
  }
  float smin = sqrtf(fmaxf(bv, 0.0f));
  float w[16], e2[16];
  float z1 = 0.f, z2 = 0.f;
  #pragma unroll
  for (int q = 0; q < 16; ++q) {
    w[q] = sqrtf(fmaxf(v[q], 0.0f)) - smin;
    z1 += __expf(-w[q]);
    e2[q] = __expf(-2.0f * w[q]);
    z2 += e2[q];
  }
  #pragma unroll
  for (int off = 32; off; off >>= 1) {
    z1 += __shfl_xor(z1, off);
    z2 += __shfl_xor(z2, off);
  }
  if (lane == 0) {
    smin_o[n] = smin;
    lz1_o[n]  = __logf(z1);
    iz2_o[n]  = 1.0f / z2;
    idx_o[n]  = bi;
  }
  // in-place bf16 planes over the consumed physical row
  ushort* prow = (ushort*)drow;
  #pragma unroll
  for (int c = 0; c < 4; ++c) {
    ushort4 hp, hw;
    hp.x = bf16_rne(e2[c*4+0]); hp.y = bf16_rne(e2[c*4+1]);
    hp.z = bf16_rne(e2[c*4+2]); hp.w = bf16_rne(e2[c*4+3]);
    hw.x = bf16_rne(w[c*4+0]);  hw.y = bf16_rne(w[c*4+1]);
    hw.z = bf16_rne(w[c*4+2]);  hw.w = bf16_rne(w[c*4+3]);
    *(ushort4*)(prow + c * 256 + lane * 4) = hp;
    *(ushort4*)(prow + 1024 + c * 256 + lane * 4) = hw;
  }
  const float* erow = E + (size_t)bi * DD;
  const float* xrow = X + (size_t)n * DD;
  #pragma unroll
  for (int p = 0; p < 4; ++p) {
    int dd = p * 64 + lane;
    float xv = xrow[dd];
    float ev = erow[dd];
    qout[(size_t)n * DD + dd] = xv + (ev - xv);
  }
}

// ---------------------------------------------------------------------------
// Kernel 4 (pure bf16 MFMA GEMM): S = -izP[b]*(sum pa*wv) - lzQ[c]
// Planes are t-major: block (t,z) streams the CONTIGUOUS slab of physical
// rows [t*64, t*64+64) — 128 KB per plane region, perfect prefetch.
__global__ __launch_bounds__(512) void k_sgemm(float* __restrict__ ws) {
  const int z = blockIdx.y;
  const int t = blockIdx.x;
  const ushort* P = (const ushort*)(ws + (z ? OFF_DV : OFF_DA));  // pa rows
  const ushort* Q = (const ushort*)(ws + (z ? OFF_DA : OFF_DV));  // wv rows
  const float* iz2_p  = ws + (z ? OFF_IZ2_V  : OFF_IZ2_A);
  const float* lz1_q  = ws + (z ? OFF_LZ1_A  : OFF_LZ1_V);
  float* S = ws + (z ? OFF_S2 : OFF_S1);
  float* part = ws + OFF_PART;

  __shared__ __align__(16) ushort PAs[2][64 * 64];
  __shared__ __align__(16) ushort WQs[2][64 * 64];
  __shared__ float redmin[8];

  const int tid = threadIdx.x;
  const int wv = tid >> 6, lane = tid & 63;
  const int rl = lane & 15, kg = lane >> 4;
  const int bt  = (wv & 3) * 16;      // wave b-tile base
  const int ctl = (wv >> 2) * 32;     // wave c-half base

  const int sr = tid >> 3, sg = tid & 7;       // sr = b row within slab
  const int lg = sg ^ (sr & 7);
  const ushort* gP = P + ((size_t)(t * 64 + sr)) * 2048 + lg * 8;
  const ushort* gQ = Q + ((size_t)(t * 64 + sr)) * 2048 + 1024 + lg * 8;
  const int dso = tid * 8;

  const int ra = bt + rl;
  const int rb0 = ctl + rl, rb1 = ctl + 16 + rl;
  int aoff[2], b0off[2], b1off[2];
  #pragma unroll
  for (int ks = 0; ks < 2; ++ks) {
    int g = ks * 4 + kg;
    aoff[ks]  = ra  * 64 + ((g ^ (ra  & 7)) * 8);
    b0off[ks] = rb0 * 64 + ((g ^ (rb0 & 7)) * 8);
    b1off[ks] = rb1 * 64 + ((g ^ (rb1 & 7)) * 8);
  }

  f32x4 acc0 = {}, acc1 = {};

  gload_lds16u(gP, &PAs[0][dso]);
  gload_lds16u(gQ, &WQs[0][dso]);
  __syncthreads();

  for (int ch = 0; ch < 16; ++ch) {
    const int cur = ch & 1;
    if (ch < 15) {
      gload_lds16u(gP + (ch + 1) * 64, &PAs[cur ^ 1][dso]);
      gload_lds16u(gQ + (ch + 1) * 64, &WQs[cur ^ 1][dso]);
    }
    __builtin_amdgcn_s_setprio(1);
    #pragma unroll
    for (int ks = 0; ks < 2; ++ks) {
      bf16x8 af = *(const bf16x8*)(&PAs[cur][aoff[ks]]);
      bf16x8 b0 = *(const bf16x8*)(&WQs[cur][b0off[ks]]);
      bf16x8 b1 = *(const bf16x8*)(&WQs[cur][b1off[ks]]);
      acc0 = __builtin_amdgcn_mfma_f32_16x16x32_bf16(af, b0, acc0, 0, 0, 0);
      acc1 = __builtin_amdgcn_mfma_f32_16x16x32_bf16(af, b1, acc1, 0, 0, 0);
    }
    __builtin_amdgcn_s_setprio(0);
    __syncthreads();   // next chunk landed + this chunk fully read
  }

  const float lzq0 = lz1_q[(size_t)rb0 * TT + t];
  const float lzq1 = lz1_q[(size_t)rb1 * TT + t];
  float mn = 3.4e38f;
  #pragma unroll
  for (int v = 0; v < 4; ++v) {
    const int b = bt + kg * 4 + v;
    const float izb = iz2_p[(size_t)b * TT + t];
    float s0 = -izb * acc0[v] - lzq0;
    float s1 = -izb * acc1[v] - lzq1;
    S[((size_t)t * 64 + b) * 64 + rb0] = s0;
    S[((size_t)t * 64 + b) * 64 + rb1] = s1;
    mn = fminf(mn, fminf(s0, s1));
  }
  #pragma unroll
  for (int off = 32; off; off >>= 1) mn = fminf(mn, __shfl_xor(mn, off));
  if (lane == 0) redmin[wv] = mn;
  __syncthreads();
  if (tid == 0) {
    float m = redmin[0];
    #pragma unroll
    for (int i = 1; i < 8; ++i) m = fminf(m, redmin[i]);
    part[z * 128 + t] = m;
  }
}

// ---------------------------------------------------------------------------
// Kernel 5: loss rows; Max computed in-block from part[] (fmin exact).
__global__ __launch_bounds__(256) void k_loss(float* __restrict__ ws) {
  const int lane = threadIdx.x & 63, wid = threadIdx.x >> 6;
  const float* part = ws + OFF_PART;
  __shared__ float red[4];
  __shared__ float smax[2];
  float m = part[threadIdx.x];
  #pragma unroll
  for (int off = 32; off; off >>= 1) m = fminf(m, __shfl_xor(m, off));
  if (lane == 0) red[wid] = m;
  __syncthreads();
  if (threadIdx.x == 0)   smax[0] = -fminf(red[0], red[1]);
  if (threadIdx.x == 128) smax[1] = -fminf(red[2], red[3]);
  __syncthreads();

  const int wglobal = blockIdx.x * 4 + wid;   // 0..1023
  double acc = 0.0;
  #pragma unroll 4
  for (int r = 0; r < 16; ++r) {
    int gw = wglobal * 16 + r;                // 0..16383
    int tens = gw >> 13;
    int rem = gw & 8191;                      // t*64 + b
    const float* S = ws + (tens ? OFF_S2 : OFF_S1);
    float maxv = smax[tens];
    float ev = __expf(S[(size_t)rem * 64 + lane] + maxv);
    float sum = ev;
    #pragma unroll
    for (int off = 32; off; off >>= 1) sum += __shfl_xor(sum, off);
    float diag = __shfl(ev, rem & 63);
    if (lane == 0) acc += (double)__logf(diag / (sum + 1e-5f));
  }
  __shared__ double dred[4];
  if (lane == 0) dred[wid] = acc;
  __syncthreads();
  if (threadIdx.x == 0)
    ((double*)(ws + OFF_PACC))[blockIdx.x] = dred[0] + dred[1] + dred[2] + dred[3];
}

// Kernel 6: reduce 256 per-block partials, finalize loss
__global__ void k_fin(const float* __restrict__ ws, float* __restrict__ out) {
  const double* p = (const double*)(ws + OFF_PACC);
  const int lane = threadIdx.x & 63, wid = threadIdx.x >> 6;
  double v = p[threadIdx.x];
  #pragma unroll
  for (int off = 32; off; off >>= 1) v += __shfl_xor(v, off);
  __shared__ double red[4];
  if (lane == 0) red[wid] = v;
  __syncthreads();
  if (threadIdx.x == 0)
    out[0] = (float)(-(red[0] + red[1] + red[2] + red[3]) / 16384.0);
}

// ---------------------------------------------------------------------------
extern "C" void kernel_launch(void* const* d_in, const int* in_sizes, int n_in,
                              void* d_out, int out_size, void* d_ws, size_t ws_size,
                              hipStream_t stream) {
  const float* A = (const float*)d_in[0];
  const float* V = (const float*)d_in[1];
  const float* E = (const float*)d_in[2];
  float* out = (float*)d_out;
  float* ws  = (float*)d_ws;

  k_sumsq  <<<dim3(4352), dim3(256), 0, stream>>>(A, V, E, ws);
  k_dist   <<<dim3(8, 64, 2), dim3(256), 0, stream>>>(A, V, E, ws);
  k_rowstats<<<dim3(2048, 2), dim3(256), 0, stream>>>(A, V, E, ws, out);
  k_sgemm  <<<dim3(128, 2), dim3(512), 0, stream>>>(ws);
  k_loss   <<<dim3(256), dim3(256), 0, stream>>>(ws);
  k_fin    <<<dim3(1), dim3(256), 0, stream>>>(ws, out);
}